// Round 11
// baseline (93151.392 us; speedup 1.0000x reference)
//
#include <hip/hip_runtime.h>
#include <cstdint>

// ---------------------------------------------------------------------------
// HierarchicalGraphMemoryNetwork on MI355X — round 11
//
// Round 10's design with the asm contract the backend accepts (r10 failed to
// compile: multiple tied "+a" operands on uint4 in one asm statement).
//  - 192 AGPR-resident weight dwords = 192 NAMED uint32_t scalars, pinned
//    one per asm statement; consumed via scalar v_accvgpr_read_b32.
//  - Thread (g=tid>>2, s4=tid&3): gate rows g*8..+7, k-slice s4*64..+63.
//    Rows 0-5 in AGPR; rows 6-7 in a 128KB lane-contiguous LDS slab.
//    h-reads: 8 b128/thread; cross-lane reduce: shfl_xor(1,2) over the 4
//    slice lanes (DPP, VALU pipe); lane s4 writes rows 2*s4, 2*s4+1.
//  - Model: VALU ~1920cy, LDS ~2300cy per step, overlapped -> ~1us/step.
// ---------------------------------------------------------------------------

#define T_LEN 8192
#define IN_F  256
#define HID   256
#define GATE  1024
#define NREL  4
#define OUT_N 256

typedef _Float16 half2_t __attribute__((ext_vector_type(2)));
typedef float    f32x4  __attribute__((ext_vector_type(4)));
typedef uint32_t u32x4  __attribute__((ext_vector_type(4)));
typedef short    s16x8  __attribute__((ext_vector_type(8)));

__device__ __forceinline__ float fdot2(uint32_t w, uint32_t h, float acc) {
#if __has_builtin(__builtin_amdgcn_fdot2)
  return __builtin_amdgcn_fdot2(__builtin_bit_cast(half2_t, w),
                                __builtin_bit_cast(half2_t, h), acc, false);
#else
  asm("v_dot2_f32_f16 %0, %1, %2, %0" : "+v"(acc) : "v"(w), "v"(h));
  return acc;
#endif
}

__device__ __forceinline__ float fsig(float x) { return 1.f / (1.f + __expf(-x)); }
__device__ __forceinline__ float ftanh(float x) { return 2.f / (1.f + __expf(-2.f * x)) - 1.f; }

__device__ __forceinline__ uint32_t pack2bf(float x, float y) {
  uint32_t ux = __builtin_bit_cast(uint32_t, x);
  uint32_t uy = __builtin_bit_cast(uint32_t, y);
  uint32_t rx = (ux + 0x7FFFu + ((ux >> 16) & 1u)) >> 16;
  uint32_t ry = (uy + 0x7FFFu + ((uy >> 16) & 1u)) >> 16;
  return (rx & 0xFFFFu) | (ry << 16);
}

__device__ __forceinline__ f32x4 mfma_bf(u32x4 a, u32x4 b, f32x4 c) {
  return __builtin_amdgcn_mfma_f32_16x16x32_bf16(
      __builtin_bit_cast(s16x8, a), __builtin_bit_cast(s16x8, b), c, 0, 0, 0);
}

// -------------------------- fp32 -> f16 convert ----------------------------
__global__ void f2h_kernel(const float* __restrict__ in, _Float16* __restrict__ out, int n) {
  int i = blockIdx.x * blockDim.x + threadIdx.x;
  if (i < n) out[i] = (_Float16)in[i];
}

// --------------------------- bf16 MFMA GEMM --------------------------------
__global__ __launch_bounds__(256) void gemm16_kernel(
    const float* __restrict__ A, int lda,
    const float* __restrict__ W, int ldw,
    const float* __restrict__ bias, const float* addC,
    float* C, int ldc, int K) {
  __shared__ __align__(16) char As[4096];
  __shared__ __align__(16) char Bs[4096];
  const int tid = threadIdx.x;
  const int w = tid >> 6, l = tid & 63;
  const int m0 = blockIdx.y * 64, n0 = blockIdx.x * 64;

  const int srow = tid >> 2, skq = tid & 3;
  const int sbyte = (srow * 64 + skq * 16) ^ ((srow & 3) << 4);
  const float* Ap = A + (size_t)(m0 + srow) * lda + skq * 8;
  const float* Wp = W + (size_t)(n0 + srow) * ldw + skq * 8;

  const int fr = l & 15, kb = l >> 4;
  const int ar = w * 16 + fr;
  const int abyte  = (ar * 64 + kb * 16) ^ ((ar & 3) << 4);
  const int bbyte0 = ((fr)      * 64 + kb * 16) ^ ((fr & 3) << 4);
  const int bbyte1 = ((16 + fr) * 64 + kb * 16) ^ ((fr & 3) << 4);
  const int bbyte2 = ((32 + fr) * 64 + kb * 16) ^ ((fr & 3) << 4);
  const int bbyte3 = ((48 + fr) * 64 + kb * 16) ^ ((fr & 3) << 4);

  f32x4 acc0 = {0.f,0.f,0.f,0.f}, acc1 = {0.f,0.f,0.f,0.f};
  f32x4 acc2 = {0.f,0.f,0.f,0.f}, acc3 = {0.f,0.f,0.f,0.f};

  for (int k0 = 0; k0 < K; k0 += 32) {
    float4 a0 = *(const float4*)(Ap + k0);
    float4 a1 = *(const float4*)(Ap + k0 + 4);
    float4 w0 = *(const float4*)(Wp + k0);
    float4 w1 = *(const float4*)(Wp + k0 + 4);
    u32x4 pa = {pack2bf(a0.x,a0.y), pack2bf(a0.z,a0.w), pack2bf(a1.x,a1.y), pack2bf(a1.z,a1.w)};
    u32x4 pb = {pack2bf(w0.x,w0.y), pack2bf(w0.z,w0.w), pack2bf(w1.x,w1.y), pack2bf(w1.z,w1.w)};
    *(u32x4*)(As + sbyte) = pa;
    *(u32x4*)(Bs + sbyte) = pb;
    __syncthreads();
    u32x4 af  = *(const u32x4*)(As + abyte);
    u32x4 bf0 = *(const u32x4*)(Bs + bbyte0);
    u32x4 bf1 = *(const u32x4*)(Bs + bbyte1);
    u32x4 bf2 = *(const u32x4*)(Bs + bbyte2);
    u32x4 bf3 = *(const u32x4*)(Bs + bbyte3);
    acc0 = mfma_bf(af, bf0, acc0);
    acc1 = mfma_bf(af, bf1, acc1);
    acc2 = mfma_bf(af, bf2, acc2);
    acc3 = mfma_bf(af, bf3, acc3);
    __syncthreads();
  }

  const int col = l & 15;
  const int rb  = (l >> 4) * 4;
#define EPI(ct, ACC) { \
    int n = n0 + (ct) * 16 + col; \
    float bv = bias ? bias[n] : 0.f; \
    _Pragma("unroll") \
    for (int r = 0; r < 4; ++r) { \
      int m = m0 + w * 16 + rb + r; \
      float v = ACC[r] + bv; \
      if (addC) v += addC[(size_t)m * ldc + n]; \
      C[(size_t)m * ldc + n] = v; } }
  EPI(0, acc0) EPI(1, acc1) EPI(2, acc2) EPI(3, acc3)
#undef EPI
}

// ------------------------- fp32 GEMM (finals only) -------------------------
__global__ __launch_bounds__(256) void gemm_kernel(
    const float* __restrict__ A, int lda,
    const float* __restrict__ W, int ldw,
    const float* __restrict__ bias,
    const float* addC,
    float* C, int ldc, int M, int N, int K) {
  __shared__ float As[16][64];
  __shared__ float Bs[16][64];
  const int tid = threadIdx.x;
  const int tx = tid & 15, ty = tid >> 4;
  const int m0 = blockIdx.y * 64, n0 = blockIdx.x * 64;
  const int lr = tid >> 2;
  const int lc = (tid & 3) * 4;
  float acc[4][4] = {};
  for (int k0 = 0; k0 < K; k0 += 16) {
    float4 av = *(const float4*)&A[(size_t)(m0 + lr) * lda + k0 + lc];
    float4 wv = *(const float4*)&W[(size_t)(n0 + lr) * ldw + k0 + lc];
    As[lc + 0][lr] = av.x; As[lc + 1][lr] = av.y; As[lc + 2][lr] = av.z; As[lc + 3][lr] = av.w;
    Bs[lc + 0][lr] = wv.x; Bs[lc + 1][lr] = wv.y; Bs[lc + 2][lr] = wv.z; Bs[lc + 3][lr] = wv.w;
    __syncthreads();
#pragma unroll
    for (int k = 0; k < 16; ++k) {
      float a[4], b[4];
#pragma unroll
      for (int i = 0; i < 4; ++i) a[i] = As[k][ty * 4 + i];
#pragma unroll
      for (int jj = 0; jj < 4; ++jj) b[jj] = Bs[k][tx * 4 + jj];
#pragma unroll
      for (int i = 0; i < 4; ++i)
#pragma unroll
        for (int jj = 0; jj < 4; ++jj) acc[i][jj] += a[i] * b[jj];
    }
    __syncthreads();
  }
#pragma unroll
  for (int i = 0; i < 4; ++i) {
    int m = m0 + ty * 4 + i;
#pragma unroll
    for (int jj = 0; jj < 4; ++jj) {
      int n = n0 + tx * 4 + jj;
      float v = acc[i][jj];
      if (bias) v += bias[n];
      if (addC) v += addC[(size_t)m * ldc + n];
      C[(size_t)m * ldc + n] = v;
    }
  }
}

// ------------------------------ gather -------------------------------------
__global__ void gather_kernel(const float* __restrict__ nodes,
                              const int* __restrict__ edges,
                              float* __restrict__ pair) {
  int t = blockIdx.x;
  int c = threadIdx.x;
  int e = edges[t * 2 + (c >> 8)];
  pair[(size_t)t * 512 + c] = nodes[(size_t)e * 256 + (c & 255)];
}

// ------------------------------ LSTM scan ----------------------------------
struct ScanDesc {
  const float* Xp;        // [T][1024] fp32 (incl. bias)
  const uint32_t* W;      // [1024][128] dwords of f16 Whh (row-major)
  float* out;
  int rev;
  int hstride;
};

#define ARD(dst, src) asm volatile("v_accvgpr_read_b32 %0, %1" : "=v"(dst) : "a"(src))

// iterate macro M(ri, q) over rows 0..5, quads 0..7
#define QPAIRS(M, ri) M(ri,0) M(ri,1) M(ri,2) M(ri,3) M(ri,4) M(ri,5) M(ri,6) M(ri,7)
#define ALLRQ(M) QPAIRS(M,0) QPAIRS(M,1) QPAIRS(M,2) QPAIRS(M,3) QPAIRS(M,4) QPAIRS(M,5)

__global__
__attribute__((amdgpu_flat_work_group_size(512, 512), amdgpu_waves_per_eu(2)))
void lstm_scan_ks(ScanDesc d0, ScanDesc d1, ScanDesc d2, int T) {
  ScanDesc d;
  if (blockIdx.x == 0) d = d0;
  else if (blockIdx.x == 1) d = d1;
  else d = d2;
  const float* __restrict__ Xp = d.Xp;
  const uint32_t* __restrict__ W = d.W;
  float* __restrict__ out = d.out;
  const int rev = d.rev, hstride = d.hstride;

  const int tid = threadIdx.x;               // 0..511
  const int s4 = tid & 3;                    // k-slice (64 elems)
  const int g  = tid >> 2;                   // row group (8 gate rows)

  __shared__ uint4 wl[16][512];              // 128 KiB: rows 6,7 of each group
  __shared__ float z_lds[1024];
  __shared__ uint32_t h_lds[128];            // 256 f16

  const uint32_t* wr = W + (size_t)(g * 8) * 128 + s4 * 32;

  // ---- rows 0..5: 192 named scalars in AGPRs (single-operand pins) ----
#define WDECL(ri, q) uint32_t w##ri##_##q##_0, w##ri##_##q##_1, w##ri##_##q##_2, w##ri##_##q##_3;
  ALLRQ(WDECL)
#undef WDECL
#define WLOAD(ri, q) { uint4 t_ = ((const uint4*)(wr + (ri) * 128))[q]; \
    w##ri##_##q##_0 = t_.x; w##ri##_##q##_1 = t_.y; \
    w##ri##_##q##_2 = t_.z; w##ri##_##q##_3 = t_.w; }
  ALLRQ(WLOAD)
#undef WLOAD
#define WPIN(ri, q) \
    asm volatile("" : "+a"(w##ri##_##q##_0)); \
    asm volatile("" : "+a"(w##ri##_##q##_1)); \
    asm volatile("" : "+a"(w##ri##_##q##_2)); \
    asm volatile("" : "+a"(w##ri##_##q##_3));
  ALLRQ(WPIN)
#undef WPIN

  // ---- rows 6,7 -> LDS slab (lane-contiguous: [quad][tid]) ----
  {
    const uint4* wr6 = (const uint4*)(wr + 6 * 128);
    const uint4* wr7 = (const uint4*)(wr + 7 * 128);
#pragma unroll
    for (int q = 0; q < 8; ++q) wl[q][tid] = wr6[q];
#pragma unroll
    for (int q = 0; q < 8; ++q) wl[8 + q][tid] = wr7[q];
  }

  if (tid < 128) h_lds[tid] = 0u;
  float c = 0.f;
  const int t0 = rev ? (T - 1) : 0;
  float xpi = 0.f, xpf = 0.f, xpg = 0.f, xpo = 0.f;
  if (tid < HID) {
    xpi = Xp[(size_t)t0 * GATE + tid];
    xpf = Xp[(size_t)t0 * GATE + tid + 256];
    xpg = Xp[(size_t)t0 * GATE + tid + 512];
    xpo = Xp[(size_t)t0 * GATE + tid + 768];
  }
  __syncthreads();

  const uint4* hq = ((const uint4*)h_lds) + s4 * 8;

#define DOTR(ri, q, hv) { uint32_t r0_, r1_, r2_, r3_; \
    ARD(r0_, w##ri##_##q##_0); ARD(r1_, w##ri##_##q##_1); \
    ARD(r2_, w##ri##_##q##_2); ARD(r3_, w##ri##_##q##_3); \
    acc##ri = fdot2(r0_, hv.x, acc##ri); acc##ri = fdot2(r1_, hv.y, acc##ri); \
    acc##ri = fdot2(r2_, hv.z, acc##ri); acc##ri = fdot2(r3_, hv.w, acc##ri); }
#define QSTEP(q) { uint4 hv = hq[q]; \
    DOTR(0, q, hv) DOTR(1, q, hv) DOTR(2, q, hv) \
    DOTR(3, q, hv) DOTR(4, q, hv) DOTR(5, q, hv) \
    { uint4 w6_ = wl[q][tid]; \
      acc6 = fdot2(w6_.x, hv.x, acc6); acc6 = fdot2(w6_.y, hv.y, acc6); \
      acc6 = fdot2(w6_.z, hv.z, acc6); acc6 = fdot2(w6_.w, hv.w, acc6); } \
    { uint4 w7_ = wl[8 + q][tid]; \
      acc7 = fdot2(w7_.x, hv.x, acc7); acc7 = fdot2(w7_.y, hv.y, acc7); \
      acc7 = fdot2(w7_.z, hv.z, acc7); acc7 = fdot2(w7_.w, hv.w, acc7); } }

  for (int s = 0; s < T; ++s) {
    const int t = rev ? (T - 1 - s) : s;
    float acc0 = 0.f, acc1 = 0.f, acc2 = 0.f, acc3 = 0.f;
    float acc4 = 0.f, acc5 = 0.f, acc6 = 0.f, acc7 = 0.f;

    QSTEP(0) QSTEP(1) QSTEP(2) QSTEP(3)
    QSTEP(4) QSTEP(5) QSTEP(6) QSTEP(7)

    // reduce across the 4 k-slice lanes (same row group; lanes 4g..4g+3)
#define RED(ri) acc##ri += __shfl_xor(acc##ri, 1, 64); \
                acc##ri += __shfl_xor(acc##ri, 2, 64);
    RED(0) RED(1) RED(2) RED(3) RED(4) RED(5) RED(6) RED(7)
#undef RED

    // lane s4 writes rows g*8 + 2*s4, +1
    float za = (s4 == 0) ? acc0 : (s4 == 1) ? acc2 : (s4 == 2) ? acc4 : acc6;
    float zb = (s4 == 0) ? acc1 : (s4 == 1) ? acc3 : (s4 == 2) ? acc5 : acc7;
    *(float2*)&z_lds[(g << 3) + (s4 << 1)] = make_float2(za, zb);
    __syncthreads();

    // gate phase (threads 0..255 = hidden units)
    if (tid < HID) {
      float zi = z_lds[tid]       + xpi;
      float zf = z_lds[tid + 256] + xpf;
      float zg = z_lds[tid + 512] + xpg;
      float zo = z_lds[tid + 768] + xpo;
      float ig = fsig(zi), fg = fsig(zf), gg = ftanh(zg), og = fsig(zo);
      c = fg * c + ig * gg;
      float h = og * ftanh(c);
      out[(size_t)t * hstride + tid] = h;
      ((_Float16*)h_lds)[tid] = (_Float16)h;
      int sn = (s + 1 < T) ? (s + 1) : s;
      int tn = rev ? (T - 1 - sn) : sn;
      xpi = Xp[(size_t)tn * GATE + tid];
      xpf = Xp[(size_t)tn * GATE + tid + 256];
      xpg = Xp[(size_t)tn * GATE + tid + 512];
      xpo = Xp[(size_t)tn * GATE + tid + 768];
    }
    __syncthreads();
  }
#undef QSTEP
#undef DOTR
}

// ---------------------------------------------------------------------------
extern "C" void kernel_launch(void* const* d_in, const int* in_sizes, int n_in,
                              void* d_out, int out_size, void* d_ws, size_t ws_size,
                              hipStream_t stream) {
  (void)in_sizes; (void)n_in; (void)out_size; (void)ws_size;
  const float* inputs = (const float*)d_in[0];
  const int*   edges  = (const int*)d_in[1];
  const float* memory = (const float*)d_in[2];
  const float* Wl_ih  = (const float*)d_in[3];
  const float* Wl_hh  = (const float*)d_in[4];
  const float* bl     = (const float*)d_in[5];
  const float* Wh_ih  = (const float*)d_in[6];
  const float* Wh_hh  = (const float*)d_in[7];
  const float* bh     = (const float*)d_in[8];
  const float* Win    = (const float*)d_in[9];
  const float* bin_   = (const float*)d_in[10];
  const float* We     = (const float*)d_in[11];
  const float* be     = (const float*)d_in[12];
  const float* Wn_ih  = (const float*)d_in[13];
  const float* Wn_hh  = (const float*)d_in[14];
  const float* bn     = (const float*)d_in[15];
  const float* Wmem   = (const float*)d_in[16];
  const float* bmem   = (const float*)d_in[17];
  const float* Wc_ih  = (const float*)d_in[18];
  const float* Wc_hh  = (const float*)d_in[19];
  const float* bc     = (const float*)d_in[20];
  const float* Wout   = (const float*)d_in[21];
  const float* bout   = (const float*)d_in[22];

  float* out_ptr = (float*)d_out;                       // [T][256]
  float* memvec  = out_ptr + (size_t)T_LEN * OUT_N;     // [T][256]

  // ---- workspace carve ----
  char* base = (char*)d_ws;
  size_t off = 0;
  auto carve = [&](size_t nbytes) -> void* {
    void* p = base + off; off += (nbytes + 255) & ~(size_t)255; return p;
  };
  float* XpA    = (float*)carve((size_t)T_LEN * GATE * 4);
  float* XpB    = (float*)carve((size_t)T_LEN * GATE * 4);
  float* XpC    = (float*)carve((size_t)T_LEN * GATE * 4);
  float* XpN    = (float*)carve((size_t)T_LEN * GATE * 4);
  float* lower  = (float*)carve((size_t)T_LEN * 512 * 4);
  float* higher = (float*)carve((size_t)T_LEN * 512 * 4);
  float* nodesA = (float*)carve((size_t)T_LEN * 256 * 4);
  float* nodesB = (float*)carve((size_t)T_LEN * 256 * 4);
  float* pairb  = (float*)carve((size_t)T_LEN * 512 * 4);
  float* ehb    = (float*)carve((size_t)T_LEN * 256 * 4);
  float* ctrlh  = (float*)carve((size_t)T_LEN * 256 * 4);
  uint32_t* Wl16 = (uint32_t*)carve((size_t)2 * GATE * HID * 2);
  uint32_t* Wh16 = (uint32_t*)carve((size_t)2 * GATE * HID * 2);
  uint32_t* Wn16 = (uint32_t*)carve((size_t)4 * GATE * HID * 2);
  uint32_t* Wc16 = (uint32_t*)carve((size_t)1 * GATE * HID * 2);
  const size_t WMAT = (size_t)GATE * HID / 2;

  auto f2h = [&](const float* src, uint32_t* dst, int n) {
    f2h_kernel<<<(n + 255) / 256, 256, 0, stream>>>(src, (_Float16*)dst, n);
  };
  f2h(Wl_hh, Wl16, 2 * GATE * HID);
  f2h(Wh_hh, Wh16, 2 * GATE * HID);
  f2h(Wn_hh, Wn16, 4 * GATE * HID);
  f2h(Wc_hh, Wc16, 1 * GATE * HID);

  auto gemm16 = [&](float* C, int ldc, const float* A, int lda,
                    const float* W, int ldw, const float* bias, const float* addC,
                    int M, int N, int K) {
    dim3 g(N / 64, M / 64);
    gemm16_kernel<<<g, 256, 0, stream>>>(A, lda, W, ldw, bias, addC, C, ldc, K);
  };
  auto gemm = [&](float* C, int ldc, const float* A, int lda,
                  const float* W, int ldw, const float* bias, const float* addC,
                  int M, int N, int K) {
    dim3 g(N / 64, M / 64);
    gemm_kernel<<<g, 256, 0, stream>>>(A, lda, W, ldw, bias, addC, C, ldc, M, N, K);
  };
  auto scan3 = [&](ScanDesc a, ScanDesc b, ScanDesc c, int nblk) {
    lstm_scan_ks<<<nblk, 512, 0, stream>>>(a, b, c, T_LEN);
  };
  ScanDesc dummy = {};

  // ---- G0: lower Xp + node0 Xp ----
  gemm16(XpA, GATE, inputs, IN_F, Wl_ih,               IN_F, bl,        nullptr, T_LEN, GATE, IN_F);
  gemm16(XpB, GATE, inputs, IN_F, Wl_ih + GATE * IN_F, IN_F, bl + GATE, nullptr, T_LEN, GATE, IN_F);
  gemm16(nodesA, 256, inputs, IN_F, Win, IN_F, bin_, nullptr, T_LEN, 256, IN_F);
  gather_kernel<<<T_LEN, 512, 0, stream>>>(nodesA, edges, pairb);
  gemm16(ehb, 256, pairb, 512, We + (size_t)0 * HID * 512, 512, be + 0 * HID, nullptr, T_LEN, 256, 512);
  gemm16(XpN, GATE, inputs, IN_F, Wn_ih + (size_t)0 * GATE * 512,       512, bn + 0 * GATE, nullptr, T_LEN, GATE, IN_F);
  gemm16(XpN, GATE, ehb,    256,  Wn_ih + (size_t)0 * GATE * 512 + 256, 512, nullptr,       XpN,     T_LEN, GATE, 256);

  // ---- Slot1: lower fwd/bwd + node0 ----
  scan3({XpA, Wl16,        lower,       0, 512},
        {XpB, Wl16 + WMAT, lower + 256, 1, 512},
        {XpN, Wn16,        nodesB,      0, 256}, 3);

  // ---- G1: higher Xp + node1 Xp ----
  gemm16(XpA, GATE, lower, 512, Wh_ih,              512, bh,        nullptr, T_LEN, GATE, 512);
  gemm16(XpB, GATE, lower, 512, Wh_ih + GATE * 512, 512, bh + GATE, nullptr, T_LEN, GATE, 512);
  gather_kernel<<<T_LEN, 512, 0, stream>>>(nodesB, edges, pairb);
  gemm16(ehb, 256, pairb, 512, We + (size_t)1 * HID * 512, 512, be + 1 * HID, nullptr, T_LEN, 256, 512);
  gemm16(XpN, GATE, inputs, IN_F, Wn_ih + (size_t)1 * GATE * 512,       512, bn + 1 * GATE, nullptr, T_LEN, GATE, IN_F);
  gemm16(XpN, GATE, ehb,    256,  Wn_ih + (size_t)1 * GATE * 512 + 256, 512, nullptr,       XpN,     T_LEN, GATE, 256);

  // ---- Slot2: higher fwd/bwd + node1 ----
  scan3({XpA, Wh16,        higher,       0, 512},
        {XpB, Wh16 + WMAT, higher + 256, 1, 512},
        {XpN, Wn16 + WMAT, nodesA,       0, 256}, 3);

  // ---- G2: ctrl Xp + node2 Xp ----
  gemm16(XpC, GATE, inputs, IN_F, Wc_ih,       896, bc,      nullptr, T_LEN, GATE, IN_F);
  gemm16(XpC, GATE, memory, 128,  Wc_ih + 768, 896, nullptr, XpC,     T_LEN, GATE, 128);
  gemm16(XpC, GATE, higher, 512,  Wc_ih + 256, 896, nullptr, XpC,     T_LEN, GATE, 512);
  gather_kernel<<<T_LEN, 512, 0, stream>>>(nodesA, edges, pairb);
  gemm16(ehb, 256, pairb, 512, We + (size_t)2 * HID * 512, 512, be + 2 * HID, nullptr, T_LEN, 256, 512);
  gemm16(XpN, GATE, inputs, IN_F, Wn_ih + (size_t)2 * GATE * 512,       512, bn + 2 * GATE, nullptr, T_LEN, GATE, IN_F);
  gemm16(XpN, GATE, ehb,    256,  Wn_ih + (size_t)2 * GATE * 512 + 256, 512, nullptr,       XpN,     T_LEN, GATE, 256);

  // ---- Slot3: node2 + ctrl ----
  scan3({XpN, Wn16 + 2 * WMAT, nodesB, 0, 256},
        {XpC, Wc16,            ctrlh,  0, 256}, dummy, 2);

  // ---- G3: node3 Xp ----
  gather_kernel<<<T_LEN, 512, 0, stream>>>(nodesB, edges, pairb);
  gemm16(ehb, 256, pairb, 512, We + (size_t)3 * HID * 512, 512, be + 3 * HID, nullptr, T_LEN, 256, 512);
  gemm16(XpN, GATE, inputs, IN_F, Wn_ih + (size_t)3 * GATE * 512,       512, bn + 3 * GATE, nullptr, T_LEN, GATE, IN_F);
  gemm16(XpN, GATE, ehb,    256,  Wn_ih + (size_t)3 * GATE * 512 + 256, 512, nullptr,       XpN,     T_LEN, GATE, 256);

  // ---- Slot4: node3 ----
  scan3({XpN, Wn16 + 3 * WMAT, nodesA, 0, 256}, dummy, dummy, 1);

  // ---- finals (fp32 for output precision) ----
  gemm(memvec,  256, nodesA, 256, Wmem, HID, bmem, nullptr, T_LEN, 256, HID);
  gemm(out_ptr, 256, ctrlh,  256, Wout, HID, bout, nullptr, T_LEN, 256, HID);
}